// Round 12
// baseline (769.166 us; speedup 1.0000x reference)
//
#include <hip/hip_runtime.h>
#include <hip/hip_bf16.h>
#include <stdint.h>

#define B_ROWS 16384
#define DIM 2048
#define NPH 192      // 3 segments x 32 K-tiles x 2 K-halves

typedef float f32x4 __attribute__((ext_vector_type(4)));
typedef short bf16x8 __attribute__((ext_vector_type(8)));
using u16 = unsigned short;
using u32 = unsigned int;

__device__ __forceinline__ u32 pack_bf2(float a, float b) {
  __hip_bfloat162 t = __float22bfloat162_rn(float2{a, b});
  union { __hip_bfloat162 b2; u32 u; } cv;
  cv.b2 = t;
  return cv.u;
}

__device__ __forceinline__ u16 f2bf_rne(float f) {
  union { float f; u32 u; } v;
  v.f = f;
  u32 u = v.u;
  u32 r = u + 0x7FFFu + ((u >> 16) & 1u);
  return (u16)(r >> 16);
}

__device__ __forceinline__ void gload16(const void* g, void* l) {
  __builtin_amdgcn_global_load_lds(
      (const __attribute__((address_space(1))) u32*)g,
      (__attribute__((address_space(3))) u32*)l, 16, 0, 0);
}

// ---- prep: flags (fp64 last-col dot) + x->bf16 + masked hF/hI --------------
__global__ __launch_bounds__(256) void k_prep(
    const float* __restrict__ x, const float* __restrict__ h,
    const float* __restrict__ W_ih, int* __restrict__ flags,
    u16* __restrict__ xb, u16* __restrict__ hF, u16* __restrict__ hI) {
  int row = blockIdx.x * 4 + (threadIdx.x >> 6);
  int lane = threadIdx.x & 63;
  const float* xr = x + (size_t)row * DIM;
  const float* hr = h + (size_t)row * DIM;
  const float* wr = W_ih + (size_t)(DIM - 1) * DIM;
  u16* xbr = xb + (size_t)row * DIM;
  double s = 0.0;
  u32 hp[16];
#pragma unroll
  for (int i = 0; i < 8; ++i) {
    int idx = (i * 64 + lane) * 4;
    f32x4 xv = *(const f32x4*)(xr + idx);
    f32x4 wv = *(const f32x4*)(wr + idx);
    f32x4 hv = *(const f32x4*)(hr + idx);
    s += (double)xv.x * wv.x + (double)xv.y * wv.y +
         (double)xv.z * wv.z + (double)xv.w * wv.w;
    *(uint2*)(xbr + idx) = uint2{pack_bf2(xv.x, xv.y), pack_bf2(xv.z, xv.w)};
    hp[2 * i] = pack_bf2(hv.x, hv.y);
    hp[2 * i + 1] = pack_bf2(hv.z, hv.w);
  }
#pragma unroll
  for (int off = 32; off > 0; off >>= 1) s += __shfl_xor(s, off);
  float hl = hr[DIM - 1];
  int f = (s < -1.0) ? 2 : (hl > 0.f ? 0 : (hl < 0.f ? 1 : 3));
  if (lane == 0) flags[row] = f;
  uint2 z{0u, 0u};
  u16* hFr = hF + (size_t)row * DIM;
  u16* hIr = hI + (size_t)row * DIM;
#pragma unroll
  for (int i = 0; i < 8; ++i) {
    int idx = (i * 64 + lane) * 4;
    uint2 p{hp[2 * i], hp[2 * i + 1]};
    *(uint2*)(hFr + idx) = (f == 0) ? p : z;
    *(uint2*)(hIr + idx) = (f == 1) ? p : z;
  }
}

// ---- flags only (fallback path) --------------------------------------------
__global__ __launch_bounds__(256) void k_flags_fb(
    const float* __restrict__ x, const float* __restrict__ h,
    const float* __restrict__ W_ih, int* __restrict__ flags) {
  int row = blockIdx.x * 4 + (threadIdx.x >> 6);
  int lane = threadIdx.x & 63;
  const float* xr = x + (size_t)row * DIM;
  const float* wr = W_ih + (size_t)(DIM - 1) * DIM;
  double s = 0.0;
#pragma unroll
  for (int i = 0; i < 8; ++i) {
    int idx = (i * 64 + lane) * 4;
    f32x4 xv = *(const f32x4*)(xr + idx);
    f32x4 wv = *(const f32x4*)(wr + idx);
    s += (double)xv.x * wv.x + (double)xv.y * wv.y +
         (double)xv.z * wv.z + (double)xv.w * wv.w;
  }
#pragma unroll
  for (int off = 32; off > 0; off >>= 1) s += __shfl_xor(s, off);
  if (lane == 0) {
    float hl = h[(size_t)row * DIM + (DIM - 1)];
    flags[row] = (s < -1.0) ? 2 : (hl > 0.f ? 0 : (hl < 0.f ? 1 : 3));
  }
}

// ---- convert W_ih ([N][K] already) f32 -> bf16 ------------------------------
__global__ __launch_bounds__(256) void k_convert(const float* __restrict__ src,
                                                 u16* __restrict__ dst) {
  size_t i = ((size_t)blockIdx.x * 256 + threadIdx.x) * 4;
  f32x4 v = *(const f32x4*)(src + i);
  *(uint2*)(dst + i) = uint2{pack_bf2(v.x, v.y), pack_bf2(v.z, v.w)};
}

// ---- transpose+convert [K][N] f32 -> [N][K] bf16 ----------------------------
__global__ __launch_bounds__(256) void k_transpose(const float* __restrict__ src,
                                                   u16* __restrict__ dst) {
  __shared__ float tile[32][33];
  int k0 = blockIdx.x * 32;
  int n0 = blockIdx.y * 32;
  int tx = threadIdx.x & 31;
  int ty = threadIdx.x >> 5;
#pragma unroll
  for (int i = 0; i < 4; ++i)
    tile[ty + 8 * i][tx] = src[(size_t)(k0 + ty + 8 * i) * DIM + n0 + tx];
  __syncthreads();
#pragma unroll
  for (int i = 0; i < 4; ++i)
    dst[(size_t)(n0 + ty + 8 * i) * DIM + k0 + tx] = f2bf_rne(tile[tx][ty + 8 * i]);
}

// ---- 256x128-tile GEMM, 4 waves, 3-slab rotation -> 2 blocks/CU ------------
// Fix for the lockstep serialization (phase = LDS-reads THEN MFMA, ~2600cyc):
// 2 desynced blocks/CU -> one block's MFMA cluster covers the other's read
// window (different pipes, m114). LDS 3 x 24KB = 72KB <= 80KB.
// Phase P: read 12 b128 frags from slab P%3; stage slab (P+2)%3 (6 loads);
// vmcnt(6) retires slab P+1 (in flight ~2 phases, never drains); barrier;
// lgkmcnt(0); 32 MFMA (setprio). Swizzle/FIFO/epilogue proven in R5/R6.
__global__ __launch_bounds__(256, 2) void k_gemm8(
    const u16* __restrict__ xb, const u16* __restrict__ hF,
    const u16* __restrict__ hI, const u16* __restrict__ Wih,
    const u16* __restrict__ WhhT, const u16* __restrict__ WinvT,
    const int* __restrict__ flags, const float* __restrict__ h,
    float* __restrict__ out) {
  __shared__ __attribute__((aligned(128))) char smem[73728];

  int o = blockIdx.x;                    // 1024 blocks
  int swz = (o & 7) * 128 + (o >> 3);    // XCD supertile: 8 row-panels x 16 cols
  int brow = (swz >> 4) * 256;
  int bcol = (swz & 15) * 128;

  int t = threadIdx.x;
  int lane = t & 63;
  int wave = t >> 6;                     // 0..3
  int wr = wave >> 1;                    // 0..1  (M half, 128 rows)
  int wc = wave & 1;                     // 0..1  (N half, 64 cols)

  // staging source-chunk swizzle: chunk = (lane&3) ^ ((lane>>3)&3)
  int sx16 = (((lane & 3) ^ ((lane >> 3) & 3)) << 4);
  // fragment read chunk swizzle: chunk = (lane>>4) ^ ((lane>>1)&3)
  int fA = (((lane >> 4) ^ ((lane >> 1) & 3)) << 4);
  int arowbase = wr * 128 + (lane & 15);
  int browbase = wc * 64 + (lane & 15);

  // stage one K-half slab (A 256x32 = 16KB, B 128x32 = 8KB) into slot p
  auto stage = [&](int T, int p) {
    if (T >= NPH) T -= NPH;
    int seg = T >> 6;
    int kt = (T >> 1) & 31;
    int kk = T & 1;
    const u16* Am = seg == 0 ? xb : (seg == 1 ? hF : hI);
    const u16* Bm = seg == 0 ? Wih : (seg == 1 ? WhhT : WinvT);
    size_t kb = (size_t)kt * 128 + (size_t)kk * 64 + (size_t)sx16;
    char* pb = smem + p * 24576;
#pragma unroll
    for (int i = 0; i < 4; ++i) {
      int r = brow + wave * 64 + i * 16 + (lane >> 2);
      gload16((const char*)Am + (size_t)r * (DIM * 2) + kb,
              pb + wave * 4096 + i * 1024);
    }
#pragma unroll
    for (int i = 0; i < 2; ++i) {
      int r = bcol + wave * 32 + i * 16 + (lane >> 2);
      gload16((const char*)Bm + (size_t)r * (DIM * 2) + kb,
              pb + 16384 + wave * 2048 + i * 1024);
    }
  };

  f32x4 acc[8][4] = {};
  bf16x8 aF[8], bF[4];

  // prologue: slabs 0,1 in flight; retire slab 0 (vmcnt(6) keeps slab 1)
  stage(0, 0);
  stage(1, 1);
  asm volatile("s_waitcnt vmcnt(6)" ::: "memory");
  __builtin_amdgcn_s_barrier();

  int pcur = 0;
#pragma unroll 1
  for (int P = 0; P < NPH; ++P) {
    const char* pb = smem + pcur * 24576;
#pragma unroll
    for (int m = 0; m < 8; ++m)
      aF[m] = *(const bf16x8*)(pb + (arowbase + m * 16) * 64 + fA);
#pragma unroll
    for (int n = 0; n < 4; ++n)
      bF[n] = *(const bf16x8*)(pb + 16384 + (browbase + n * 16) * 64 + fA);
    int pst = pcur + 2; if (pst >= 3) pst -= 3;
    stage(P + 2, pst);
    asm volatile("s_waitcnt vmcnt(6)" ::: "memory");
    __builtin_amdgcn_s_barrier();
    asm volatile("s_waitcnt lgkmcnt(0)" ::: "memory");
    __builtin_amdgcn_sched_barrier(0);
    __builtin_amdgcn_s_setprio(1);
#pragma unroll
    for (int m = 0; m < 8; ++m)
#pragma unroll
      for (int n = 0; n < 4; ++n)
        acc[m][n] = __builtin_amdgcn_mfma_f32_16x16x32_bf16(
            aF[m], bF[n], acc[m][n], 0, 0, 0);
    __builtin_amdgcn_s_setprio(0);
    pcur = (pcur == 2) ? 0 : pcur + 1;
  }
  asm volatile("s_waitcnt vmcnt(0)" ::: "memory");

  // epilogue: C mapping col=lane&15, row=(lane>>4)*4+j (proven layout)
#pragma unroll
  for (int mi = 0; mi < 8; ++mi) {
    int rbase = brow + wr * 128 + mi * 16 + (lane >> 4) * 4;
#pragma unroll
    for (int j = 0; j < 4; ++j) {
      int row = rbase + j;
      bool pass = (flags[row] == 2);
#pragma unroll
      for (int n = 0; n < 4; ++n) {
        int col = bcol + wc * 64 + n * 16 + (lane & 15);
        float v = acc[mi][n][j];
        if (pass) v += h[(size_t)row * DIM + col];
        out[(size_t)row * DIM + col] = v;
      }
    }
  }
}

// ---- fallback (ws too small): R1 reg-staged 3-segment masked GEMM -----------
#define BM 128
#define BN 128
#define BK 64
__global__ __launch_bounds__(256, 2) void k_gemm_fb(
    const float* __restrict__ x, const float* __restrict__ h,
    const u16* __restrict__ Wih, const u16* __restrict__ WhhT,
    const u16* __restrict__ WinvT, const int* __restrict__ flags,
    float* __restrict__ out) {
  __shared__ char smem[(BM + BN) * BK * 2];
  char* sA = smem;
  char* sB = smem + BM * BK * 2;

  int o = blockIdx.x;
  int swz = (o & 7) * ((int)gridDim.x >> 3) + (o >> 3);
  int brow = (swz >> 4) * BM;
  int bcol = (swz & 15) * BN;

  int t = threadIdx.x;
  int lane = t & 63;
  int wave = t >> 6;
  int wrow = (wave >> 1) * 64;
  int wcol = (wave & 1) * 64;

  f32x4 acc[4][4] = {};
  int sc = t & 15;
  int sr0 = t >> 4;

  int aOff[4][2], bOff[4][2];
#pragma unroll
  for (int m = 0; m < 4; ++m)
#pragma unroll
    for (int kk = 0; kk < 2; ++kk) {
      int ar = wrow + m * 16 + (lane & 15);
      aOff[m][kk] = ar * (BK * 2) + ((kk * 64 + (lane >> 4) * 16) ^ ((ar & 7) << 4));
      int br = wcol + m * 16 + (lane & 15);
      bOff[m][kk] = br * (BK * 2) + ((kk * 64 + (lane >> 4) * 16) ^ ((br & 7) << 4));
    }

#pragma unroll 1
  for (int seg = 0; seg < 3; ++seg) {
    const float* Asrc = (seg == 0) ? x : h;
    const u16* Bsrc = (seg == 0) ? Wih : (seg == 1) ? WhhT : WinvT;
    int want = seg - 1;

    float rmask[8];
#pragma unroll
    for (int i = 0; i < 8; ++i) {
      int r = sr0 + 16 * i;
      rmask[i] = (want < 0 || flags[brow + r] == want) ? 1.f : 0.f;
    }

#pragma unroll 1
    for (int k0 = 0; k0 < DIM; k0 += BK) {
      __syncthreads();
#pragma unroll
      for (int i = 0; i < 8; ++i) {
        int r = sr0 + 16 * i;
        f32x4 v = *(const f32x4*)(Asrc + (size_t)(brow + r) * DIM + k0 + sc * 4);
        float msk = rmask[i];
        int off = r * (BK * 2) + ((sc * 8) ^ ((r & 7) << 4));
        *(uint2*)(sA + off) =
            uint2{pack_bf2(v.x * msk, v.y * msk), pack_bf2(v.z * msk, v.w * msk)};
      }
#pragma unroll
      for (int i = 0; i < 4; ++i) {
        int ch = t + 256 * i;
        int r = ch >> 3;
        int c = ch & 7;
        uint4 v = *(const uint4*)(Bsrc + (size_t)(bcol + r) * DIM + k0 + c * 8);
        int off = r * (BK * 2) + ((c * 16) ^ ((r & 7) << 4));
        *(uint4*)(sB + off) = v;
      }
      __syncthreads();
      bf16x8 aF2[4][2], bF2[4][2];
#pragma unroll
      for (int m = 0; m < 4; ++m)
#pragma unroll
        for (int kk = 0; kk < 2; ++kk) {
          aF2[m][kk] = *(const bf16x8*)(sA + aOff[m][kk]);
          bF2[m][kk] = *(const bf16x8*)(sB + bOff[m][kk]);
        }
#pragma unroll
      for (int kk = 0; kk < 2; ++kk)
#pragma unroll
        for (int m = 0; m < 4; ++m)
#pragma unroll
          for (int n = 0; n < 4; ++n)
            acc[m][n] = __builtin_amdgcn_mfma_f32_16x16x32_bf16(
                aF2[m][kk], bF2[n][kk], acc[m][n], 0, 0, 0);
    }
  }

#pragma unroll
  for (int m = 0; m < 4; ++m) {
    int rbase = brow + wrow + m * 16 + (lane >> 4) * 4;
#pragma unroll
    for (int j = 0; j < 4; ++j) {
      int row = rbase + j;
      bool pass = (flags[row] == 2);
#pragma unroll
      for (int n = 0; n < 4; ++n) {
        int col = bcol + wcol + n * 16 + (lane & 15);
        float v = acc[m][n][j];
        if (pass) v += h[(size_t)row * DIM + col];
        out[(size_t)row * DIM + col] = v;
      }
    }
  }
}

extern "C" void kernel_launch(void* const* d_in, const int* in_sizes, int n_in,
                              void* d_out, int out_size, void* d_ws, size_t ws_size,
                              hipStream_t stream) {
  const float* x = (const float*)d_in[0];
  const float* h = (const float*)d_in[1];
  const float* W_ih = (const float*)d_in[2];
  const float* W_hh = (const float*)d_in[3];
  const float* W_inv = (const float*)d_in[4];
  float* out = (float*)d_out;

  char* ws = (char*)d_ws;
  int* flags = (int*)ws;                               // 64 KB
  u16* WihB = (u16*)(ws + (64 << 10));                 // 8 MB
  u16* WhhT = WihB + (size_t)DIM * DIM;                // 8 MB
  u16* WinvT = WhhT + (size_t)DIM * DIM;               // 8 MB
  u16* xb = WinvT + (size_t)DIM * DIM;                 // 64 MB
  u16* hF = xb + (size_t)B_ROWS * DIM;                 // 64 MB
  u16* hI = hF + (size_t)B_ROWS * DIM;                 // 64 MB
  size_t need = (size_t)(64 << 10) + 3ull * DIM * DIM * 2 + 3ull * B_ROWS * DIM * 2;

  k_convert<<<(DIM * DIM / 4) / 256, 256, 0, stream>>>(W_ih, WihB);
  k_transpose<<<dim3(DIM / 32, DIM / 32), 256, 0, stream>>>(W_hh, WhhT);
  k_transpose<<<dim3(DIM / 32, DIM / 32), 256, 0, stream>>>(W_inv, WinvT);

  if (ws_size >= need) {
    k_prep<<<B_ROWS / 4, 256, 0, stream>>>(x, h, W_ih, flags, xb, hF, hI);
    k_gemm8<<<(B_ROWS / 256) * (DIM / 128), 256, 0, stream>>>(
        xb, hF, hI, WihB, WhhT, WinvT, flags, h, out);
  } else {
    k_flags_fb<<<B_ROWS / 4, 256, 0, stream>>>(x, h, W_ih, flags);
    k_gemm_fb<<<(B_ROWS / BM) * (DIM / BN), 256, 0, stream>>>(x, h, WihB, WhhT,
                                                              WinvT, flags, out);
  }
}

// Round 13
// 492.005 us; speedup vs baseline: 1.5633x; 1.5633x over previous
//
#include <hip/hip_runtime.h>
#include <hip/hip_bf16.h>
#include <stdint.h>

#define B_ROWS 16384
#define DIM 2048
#define MAXPR 17152   // 67 * 256 max padded rows

typedef float f32x4 __attribute__((ext_vector_type(4)));
typedef short bf16x8 __attribute__((ext_vector_type(8)));
using u16 = unsigned short;
using u32 = unsigned int;

__device__ __forceinline__ u32 pack_bf2(float a, float b) {
  __hip_bfloat162 t = __float22bfloat162_rn(float2{a, b});
  union { __hip_bfloat162 b2; u32 u; } cv;
  cv.b2 = t;
  return cv.u;
}

__device__ __forceinline__ u16 f2bf_rne(float f) {
  union { float f; u32 u; } v;
  v.f = f;
  u32 u = v.u;
  u32 r = u + 0x7FFFu + ((u >> 16) & 1u);
  return (u16)(r >> 16);
}

__device__ __forceinline__ void gload16(const void* g, void* l) {
  __builtin_amdgcn_global_load_lds(
      (const __attribute__((address_space(1))) u32*)g,
      (__attribute__((address_space(3))) u32*)l, 16, 0, 0);
}

// ---- prep2: flags (fp64 last-col dot) + x->bf16 + h->bf16 (natural order) --
__global__ __launch_bounds__(256) void k_prep2(
    const float* __restrict__ x, const float* __restrict__ h,
    const float* __restrict__ W_ih, int* __restrict__ flags,
    u16* __restrict__ xb, u16* __restrict__ hb) {
  int row = blockIdx.x * 4 + (threadIdx.x >> 6);
  int lane = threadIdx.x & 63;
  const float* xr = x + (size_t)row * DIM;
  const float* hr = h + (size_t)row * DIM;
  const float* wr = W_ih + (size_t)(DIM - 1) * DIM;
  u16* xbr = xb + (size_t)row * DIM;
  u16* hbr = hb + (size_t)row * DIM;
  double s = 0.0;
#pragma unroll
  for (int i = 0; i < 8; ++i) {
    int idx = (i * 64 + lane) * 4;
    f32x4 xv = *(const f32x4*)(xr + idx);
    f32x4 wv = *(const f32x4*)(wr + idx);
    f32x4 hv = *(const f32x4*)(hr + idx);
    s += (double)xv.x * wv.x + (double)xv.y * wv.y +
         (double)xv.z * wv.z + (double)xv.w * wv.w;
    *(uint2*)(xbr + idx) = uint2{pack_bf2(xv.x, xv.y), pack_bf2(xv.z, xv.w)};
    *(uint2*)(hbr + idx) = uint2{pack_bf2(hv.x, hv.y), pack_bf2(hv.z, hv.w)};
  }
#pragma unroll
  for (int off = 32; off > 0; off >>= 1) s += __shfl_xor(s, off);
  if (lane == 0) {
    float hl = hr[DIM - 1];
    flags[row] = (s < -1.0) ? 2 : (hl > 0.f ? 0 : (hl < 0.f ? 1 : 3));
  }
}

// ---- scan: deterministic compaction order (single block, no atomics) -------
__global__ __launch_bounds__(256) void k_scan(const int* __restrict__ flags,
                                              int* __restrict__ iperm,
                                              int* __restrict__ meta) {
  __shared__ int sF[257], sI[257], sP[257];
  int t = threadIdx.x;
  int cF = 0, cI = 0, cP = 0;
  for (int i = 0; i < 64; ++i) {
    int f = flags[t * 64 + i];
    cF += (f == 0); cI += (f == 1); cP += (f >= 2);
  }
  sF[t + 1] = cF; sI[t + 1] = cI; sP[t + 1] = cP;
  for (int i = t; i < MAXPR; i += 256) iperm[i] = -1;
  __syncthreads();
  if (t == 0) {
    sF[0] = sI[0] = sP[0] = 0;
    for (int i = 1; i <= 256; ++i) {
      sF[i] += sF[i - 1]; sI[i] += sI[i - 1]; sP[i] += sP[i - 1];
    }
  }
  __syncthreads();
  int totF = sF[256], totI = sI[256], totP = sP[256];
  int padF = (totF + 255) & ~255;
  int padI = (totI + 255) & ~255;
  int rowsFI = padF + padI;
  int nrows = rowsFI + totP;
  if (t == 0) {
    meta[0] = (nrows + 255) >> 8;   // nrt
    meta[1] = rowsFI >> 8;          // tilesFI
    meta[2] = rowsFI;
    meta[3] = padF;
  }
  int oF = sF[t], oI = padF + sI[t], oP = rowsFI + sP[t];
  for (int i = 0; i < 64; ++i) {
    int r = t * 64 + i;
    int f = flags[r];
    if (f == 0) iperm[oF++] = r;
    else if (f == 1) iperm[oI++] = r;
    else iperm[oP++] = r;
  }
}

// ---- convert W_ih ([N][K] already) f32 -> bf16 ------------------------------
__global__ __launch_bounds__(256) void k_convert(const float* __restrict__ src,
                                                 u16* __restrict__ dst) {
  size_t i = ((size_t)blockIdx.x * 256 + threadIdx.x) * 4;
  f32x4 v = *(const f32x4*)(src + i);
  *(uint2*)(dst + i) = uint2{pack_bf2(v.x, v.y), pack_bf2(v.z, v.w)};
}

// ---- transpose+convert [K][N] f32 -> [N][K] bf16 ----------------------------
__global__ __launch_bounds__(256) void k_transpose(const float* __restrict__ src,
                                                   u16* __restrict__ dst) {
  __shared__ float tile[32][33];
  int k0 = blockIdx.x * 32;
  int n0 = blockIdx.y * 32;
  int tx = threadIdx.x & 31;
  int ty = threadIdx.x >> 5;
#pragma unroll
  for (int i = 0; i < 4; ++i)
    tile[ty + 8 * i][tx] = src[(size_t)(k0 + ty + 8 * i) * DIM + n0 + tx];
  __syncthreads();
#pragma unroll
  for (int i = 0; i < 4; ++i)
    dst[(size_t)(n0 + ty + 8 * i) * DIM + k0 + tx] = f2bf_rne(tile[tx][ty + 8 * i]);
}

// ---- 256^2 2-phase/K-tile pipelined GEMM over VIRTUALLY-compacted rows ------
// R8's proven schedule (369us): counted vmcnt(8) FIFO, 1 barrier/phase,
// setprio MFMA, swizzled slabs. Change vs R8: no physical row permute --
// A-staging gathers rows through iperm via per-lane global source addresses
// (global_load_lds src is per-lane; LDS dest stays wave-uniform+linear).
// Row offsets looked up ONCE per job, held in registers for all phases.
// Pad rows (iperm<0) clamp to row 0; epilogue skips them.
__global__ __launch_bounds__(512, 2) void k_gemm8(
    const u16* __restrict__ xb, const u16* __restrict__ hb,
    const u16* __restrict__ Wih, const u16* __restrict__ WhhT,
    const u16* __restrict__ WinvT, const int* __restrict__ iperm,
    const int* __restrict__ flags, const int* __restrict__ meta,
    const float* __restrict__ h, float* __restrict__ out) {
  __shared__ __attribute__((aligned(128))) char smem[131072];

  int o = blockIdx.x;                    // identity order: long tiles first
  int rt = o >> 3;
  int bcol = (o & 7) * 256;
  int brow = rt * 256;

  int nrt = meta[0];
  int tilesFI = meta[1];
  int tilesF = meta[3] >> 8;
  if (rt >= nrt) return;
  const int NTb = (rt < tilesFI) ? 64 : 32;
  const u16* Bh = (rt < tilesF) ? WhhT : WinvT;

  int t = threadIdx.x;
  int lane = t & 63;
  int wave = t >> 6;
  int wr = wave >> 2;                    // 0..1  (M half)
  int wc = wave & 3;                     // 0..3  (N quarter)

  // staging source-chunk swizzle: chunk = (lane&3) ^ ((lane>>3)&3)
  int sx16 = (((lane & 3) ^ ((lane >> 3) & 3)) << 4);
  // fragment read chunk swizzle: chunk = (lane>>4) ^ ((lane>>1)&3)
  int fA = (((lane >> 4) ^ ((lane >> 1) & 3)) << 4);
  int arowbase = wr * 128 + (lane & 15);
  int browbase = wc * 64 + (lane & 15);

  // per-job A-row gather: this thread's 2 staging rows, resolved once
  int pr0 = brow + wave * 32 + (lane >> 2);
  int rA0 = iperm[pr0];      if (rA0 < 0) rA0 = 0;
  int rA1 = iperm[pr0 + 16]; if (rA1 < 0) rA1 = 0;
  size_t aoff0 = (size_t)rA0 * (DIM * 2) + sx16;
  size_t aoff1 = (size_t)rA1 * (DIM * 2) + sx16;
  size_t boff = (size_t)(bcol + wave * 32 + (lane >> 2)) * (DIM * 2) + sx16;

  auto stage = [&](int T, int isB, int kk) {
    if (T >= NTb) T -= NTb;
    int s = T >> 5;                      // 0: x-seg, 1: h-seg
    int kt = T & 31;
    size_t kb = (size_t)kt * 128 + (size_t)kk * 64;
    char* ldst = smem + ((T & 1) << 16) + kk * 32768 + isB * 16384 +
                 (wave * 32) * 64;
    if (isB) {
      const char* mat = (const char*)(s ? Bh : Wih);
      gload16(mat + boff + kb, ldst);
      gload16(mat + boff + (size_t)16 * (DIM * 2) + kb, ldst + 1024);
    } else {
      const char* mat = (const char*)(s ? hb : xb);
      gload16(mat + aoff0 + kb, ldst);
      gload16(mat + aoff1 + kb, ldst + 1024);
    }
  };

  f32x4 acc[8][4] = {};
  bf16x8 aF[8], bF[4];

  // prologue FIFO: [(0,k0 pair),(0,k1 pair),(1,k0 pair)]; retire (0,k0).
  stage(0, 0, 0); stage(0, 1, 0);
  stage(0, 0, 1); stage(0, 1, 1);
  stage(1, 0, 0); stage(1, 1, 0);
  asm volatile("s_waitcnt vmcnt(8)" ::: "memory");
  __builtin_amdgcn_s_barrier();

#define PHASE(KK, STT, STKK)                                                   \
  {                                                                            \
    const char* Ab_ = smem + buf + (KK) * 32768;                               \
    _Pragma("unroll") for (int m = 0; m < 4; ++m) {                            \
      aF[m] = *(const bf16x8*)(Ab_ + (arowbase + m * 16) * 64 + fA);           \
      aF[4 + m] = *(const bf16x8*)(Ab_ + (arowbase + 64 + m * 16) * 64 + fA);  \
    }                                                                          \
    _Pragma("unroll") for (int n = 0; n < 4; ++n)                              \
        bF[n] = *(const bf16x8*)(Ab_ + 16384 + (browbase + n * 16) * 64 + fA); \
    stage(STT, 0, STKK);                                                       \
    stage(STT, 1, STKK);                                                       \
    asm volatile("s_waitcnt vmcnt(8)" ::: "memory");                           \
    __builtin_amdgcn_s_barrier();                                              \
    asm volatile("s_waitcnt lgkmcnt(0)" ::: "memory");                         \
    __builtin_amdgcn_sched_barrier(0);                                         \
    __builtin_amdgcn_s_setprio(1);                                             \
    _Pragma("unroll") for (int mh = 0; mh < 2; ++mh)                           \
        _Pragma("unroll") for (int m = 0; m < 4; ++m)                          \
            _Pragma("unroll") for (int n = 0; n < 4; ++n)                      \
                acc[mh * 4 + m][n] = __builtin_amdgcn_mfma_f32_16x16x32_bf16(  \
                    aF[mh * 4 + m], bF[n], acc[mh * 4 + m][n], 0, 0, 0);       \
    __builtin_amdgcn_s_setprio(0);                                             \
  }

#pragma unroll 1
  for (int T = 0; T < NTb; ++T) {
    const int buf = (T & 1) << 16;
    PHASE(0, T + 1, 1)
    PHASE(1, T + 2, 0)
  }
#undef PHASE
  asm volatile("s_waitcnt vmcnt(0)" ::: "memory");

  // epilogue: scatter rows via iperm; add h for flag==2 (pass) rows
#pragma unroll
  for (int mi = 0; mi < 8; ++mi) {
    int pbase = brow + wr * 128 + (mi >> 2) * 64 + (mi & 3) * 16 +
                (lane >> 4) * 4;
#pragma unroll
    for (int j = 0; j < 4; ++j) {
      int p = pbase + j;
      int orig = iperm[p];
      if (orig >= 0) {
        bool pass = (flags[orig] == 2);
#pragma unroll
        for (int n = 0; n < 4; ++n) {
          int col = bcol + wc * 64 + n * 16 + (lane & 15);
          float v = acc[mi][n][j];
          if (pass) v += h[(size_t)orig * DIM + col];
          out[(size_t)orig * DIM + col] = v;
        }
      }
    }
  }
}

// ---- fallback (ws too small): reg-staged 3-segment masked GEMM --------------
#define BM 128
#define BN 128
#define BK 64
__global__ __launch_bounds__(256, 2) void k_gemm_fb(
    const float* __restrict__ x, const float* __restrict__ h,
    const u16* __restrict__ Wih, const u16* __restrict__ WhhT,
    const u16* __restrict__ WinvT, const int* __restrict__ flags,
    float* __restrict__ out) {
  __shared__ char smem[(BM + BN) * BK * 2];
  char* sA = smem;
  char* sB = smem + BM * BK * 2;

  int o = blockIdx.x;
  int swz = (o & 7) * ((int)gridDim.x >> 3) + (o >> 3);
  int brow = (swz >> 4) * BM;
  int bcol = (swz & 15) * BN;

  int t = threadIdx.x;
  int lane = t & 63;
  int wave = t >> 6;
  int wrow = (wave >> 1) * 64;
  int wcol = (wave & 1) * 64;

  f32x4 acc[4][4] = {};
  int sc = t & 15;
  int sr0 = t >> 4;

  int aOff[4][2], bOff[4][2];
#pragma unroll
  for (int m = 0; m < 4; ++m)
#pragma unroll
    for (int kk = 0; kk < 2; ++kk) {
      int ar = wrow + m * 16 + (lane & 15);
      aOff[m][kk] = ar * (BK * 2) + ((kk * 64 + (lane >> 4) * 16) ^ ((ar & 7) << 4));
      int br = wcol + m * 16 + (lane & 15);
      bOff[m][kk] = br * (BK * 2) + ((kk * 64 + (lane >> 4) * 16) ^ ((br & 7) << 4));
    }

#pragma unroll 1
  for (int seg = 0; seg < 3; ++seg) {
    const float* Asrc = (seg == 0) ? x : h;
    const u16* Bsrc = (seg == 0) ? Wih : (seg == 1) ? WhhT : WinvT;
    int want = seg - 1;

    float rmask[8];
#pragma unroll
    for (int i = 0; i < 8; ++i) {
      int r = sr0 + 16 * i;
      rmask[i] = (want < 0 || flags[brow + r] == want) ? 1.f : 0.f;
    }

#pragma unroll 1
    for (int k0 = 0; k0 < DIM; k0 += BK) {
      __syncthreads();
#pragma unroll
      for (int i = 0; i < 8; ++i) {
        int r = sr0 + 16 * i;
        f32x4 v = *(const f32x4*)(Asrc + (size_t)(brow + r) * DIM + k0 + sc * 4);
        float msk = rmask[i];
        int off = r * (BK * 2) + ((sc * 8) ^ ((r & 7) << 4));
        *(uint2*)(sA + off) =
            uint2{pack_bf2(v.x * msk, v.y * msk), pack_bf2(v.z * msk, v.w * msk)};
      }
#pragma unroll
      for (int i = 0; i < 4; ++i) {
        int ch = t + 256 * i;
        int r = ch >> 3;
        int c = ch & 7;
        uint4 v = *(const uint4*)(Bsrc + (size_t)(bcol + r) * DIM + k0 + c * 8);
        int off = r * (BK * 2) + ((c * 16) ^ ((r & 7) << 4));
        *(uint4*)(sB + off) = v;
      }
      __syncthreads();
      bf16x8 aF2[4][2], bF2[4][2];
#pragma unroll
      for (int m = 0; m < 4; ++m)
#pragma unroll
        for (int kk = 0; kk < 2; ++kk) {
          aF2[m][kk] = *(const bf16x8*)(sA + aOff[m][kk]);
          bF2[m][kk] = *(const bf16x8*)(sB + bOff[m][kk]);
        }
#pragma unroll
      for (int kk = 0; kk < 2; ++kk)
#pragma unroll
        for (int m = 0; m < 4; ++m)
#pragma unroll
          for (int n = 0; n < 4; ++n)
            acc[m][n] = __builtin_amdgcn_mfma_f32_16x16x32_bf16(
                aF2[m][kk], bF2[n][kk], acc[m][n], 0, 0, 0);
    }
  }

#pragma unroll
  for (int m = 0; m < 4; ++m) {
    int rbase = brow + wrow + m * 16 + (lane >> 4) * 4;
#pragma unroll
    for (int j = 0; j < 4; ++j) {
      int row = rbase + j;
      bool pass = (flags[row] == 2);
#pragma unroll
      for (int n = 0; n < 4; ++n) {
        int col = bcol + wcol + n * 16 + (lane & 15);
        float v = acc[m][n][j];
        if (pass) v += h[(size_t)row * DIM + col];
        out[(size_t)row * DIM + col] = v;
      }
    }
  }
}

extern "C" void kernel_launch(void* const* d_in, const int* in_sizes, int n_in,
                              void* d_out, int out_size, void* d_ws, size_t ws_size,
                              hipStream_t stream) {
  const float* x = (const float*)d_in[0];
  const float* h = (const float*)d_in[1];
  const float* W_ih = (const float*)d_in[2];
  const float* W_hh = (const float*)d_in[3];
  const float* W_inv = (const float*)d_in[4];
  float* out = (float*)d_out;

  char* ws = (char*)d_ws;
  int* flags = (int*)ws;                                  // 64 KB
  int* meta = (int*)(ws + 65536);                         // 256 B
  int* iperm = (int*)(ws + 65536 + 256);                  // 67 KB
  u16* WihB = (u16*)(ws + 139264);                        // 8 MB
  u16* WhhT = WihB + (size_t)DIM * DIM;                   // 8 MB
  u16* WinvT = WhhT + (size_t)DIM * DIM;                  // 8 MB
  u16* xb = WinvT + (size_t)DIM * DIM;                    // 64 MB
  u16* hb = xb + (size_t)B_ROWS * DIM;                    // 64 MB
  size_t need = 139264 + 3ull * DIM * DIM * 2 + 2ull * B_ROWS * DIM * 2;

  k_convert<<<(DIM * DIM / 4) / 256, 256, 0, stream>>>(W_ih, WihB);
  k_transpose<<<dim3(DIM / 32, DIM / 32), 256, 0, stream>>>(W_hh, WhhT);
  k_transpose<<<dim3(DIM / 32, DIM / 32), 256, 0, stream>>>(W_inv, WinvT);

  if (ws_size >= need) {
    k_prep2<<<B_ROWS / 4, 256, 0, stream>>>(x, h, W_ih, flags, xb, hb);
    k_scan<<<1, 256, 0, stream>>>(flags, iperm, meta);
    k_gemm8<<<67 * 8, 512, 0, stream>>>(xb, hb, WihB, WhhT, WinvT, iperm,
                                        flags, meta, h, out);
  } else {
    k_prep2<<<B_ROWS / 4, 256, 0, stream>>>(x, h, W_ih, flags,
                                            (u16*)(ws + 139264),
                                            (u16*)(ws + 139264));
    k_gemm_fb<<<(B_ROWS / BM) * (DIM / BN), 256, 0, stream>>>(x, h, WihB, WhhT,
                                                              WinvT, flags, out);
  }
}